// Round 5
// baseline (380.853 us; speedup 1.0000x reference)
//
#include <hip/hip_runtime.h>
#include <stdint.h>

// Binary conv 3x3 s1 p1 — XNOR-popcount, lane-per-output-channel orientation.
//   xp padded [n][58][58][8 words], halo = 0
//   wp [o][tap][word]  (72 u32 per o, VGPR-resident per lane)
//   corrT[cfg][o], cfg = hp*3+wq:  corr = 256*nvalid + 2*sum_{invalid taps} popc(w)
//   out[n,o,s] = corr - 2 * sum_{9 taps, 8 words} popc(x ^ w)

#define N_BATCH 32
#define C_IN    256
#define HH      56
#define WW_     56
#define HW      (HH * WW_)   // 3136
#define C_OUT   256
#define WORDS   8
#define TAPS    9
#define PH      58
#define PW      58
#define CHUNK   32           // pixels per wave; 3136 = 98 * 32

// ---- pass 1: binarize + bitpack x -> padded xp ----
__global__ __launch_bounds__(256) void pack_x_kernel(const float* __restrict__ x,
                                                     uint32_t* __restrict__ xp) {
    int tid = blockIdx.x * 256 + threadIdx.x;       // 32*3136*8 = 802816
    int s = tid % HW;
    int t = tid / HW;
    int n = t % N_BATCH;
    int word = t / N_BATCH;                          // 0..7
    int h = s / WW_, w = s % WW_;
    const float* px = x + ((size_t)(n * C_IN + word * 32)) * HW + s;
    uint32_t bits = 0;
#pragma unroll
    for (int i = 0; i < 32; ++i) {
        float v = px[(size_t)i * HW];                // coalesced across lanes
        bits |= (v > 0.0f ? 1u : 0u) << i;
    }
    xp[(((size_t)n * PH + (h + 1)) * PW + (w + 1)) * WORDS + word] = bits;
}

// ---- pass 2: binarize + bitpack w -> wp[o][tap][word] ----
__global__ __launch_bounds__(256) void pack_w_kernel(const float* __restrict__ w,
                                                     uint32_t* __restrict__ wp) {
    int tid = blockIdx.x * 256 + threadIdx.x;        // 256*9*8 = 18432
    int o = tid / (TAPS * WORDS);
    int r = tid % (TAPS * WORDS);
    int tap = r / WORDS;
    int j = r % WORDS;
    uint32_t bits = 0;
#pragma unroll
    for (int i = 0; i < 32; ++i) {
        int c = j * 32 + i;
        float v = w[((size_t)(o * C_IN + c)) * TAPS + tap];
        bits |= (v > 0.0f ? 1u : 0u) << i;
    }
    wp[tid] = bits;
}

// ---- pass 2b: border-correction table corrT[cfg][o] ----
__global__ void corr_kernel(const uint32_t* __restrict__ wp,
                            uint32_t* __restrict__ corrT) {
    int o = threadIdx.x;                             // 1 block x 256
    int pc[TAPS];
#pragma unroll
    for (int tap = 0; tap < TAPS; ++tap) {
        int c = 0;
#pragma unroll
        for (int j = 0; j < WORDS; ++j)
            c += __popc(wp[((size_t)o * TAPS + tap) * WORDS + j]);
        pc[tap] = c;
    }
#pragma unroll
    for (int hp = 0; hp < 3; ++hp) {
#pragma unroll
        for (int wq = 0; wq < 3; ++wq) {
            int nv = (hp == 1 ? 3 : 2) * (wq == 1 ? 3 : 2);
            int sinv = 0;
#pragma unroll
            for (int kh = -1; kh <= 1; ++kh) {
#pragma unroll
                for (int kw = -1; kw <= 1; ++kw) {
                    bool inv = (kh == -1 && hp == 0) || (kh == 1 && hp == 2) ||
                               (kw == -1 && wq == 0) || (kw == 1 && wq == 2);
                    if (inv) sinv += pc[(kh + 1) * 3 + (kw + 1)];
                }
            }
            corrT[(hp * 3 + wq) * C_OUT + o] = (uint32_t)(256 * nv + 2 * sinv);
        }
    }
}

// ---- pass 3: lane = output channel, pixel = wave-uniform ----
// block (64,4): lane = threadIdx.x (o within group), wv = threadIdx.y (o-group)
// grid (98, 32): blockIdx.x = 32-pixel chunk, blockIdx.y = n
__global__ __launch_bounds__(256) void bconv2_kernel(const uint32_t* __restrict__ xp,
                                                     const uint32_t* __restrict__ wp,
                                                     const uint32_t* __restrict__ corrT,
                                                     float* __restrict__ out) {
    __shared__ float lds[4][16][65];                 // per-wave 16px x 64o tile, padded

    const int lane = threadIdx.x;                    // 0..63
    const int wv   = threadIdx.y;                    // 0..3
    const int o    = wv * 64 + lane;                 // output channel
    const int n    = blockIdx.y;
    const int s0   = blockIdx.x * CHUNK;

    // weights for this lane's o: 72 u32, VGPR-resident for the whole kernel
    uint32_t wreg[TAPS * WORDS];
    {
        const uint4* wpo = reinterpret_cast<const uint4*>(wp + (size_t)o * (TAPS * WORDS));
#pragma unroll
        for (int t = 0; t < 18; ++t)
            reinterpret_cast<uint4*>(wreg)[t] = wpo[t];
    }
    // 9 border-correction values for this lane's o
    int cc[9];
#pragma unroll
    for (int cfg = 0; cfg < 9; ++cfg)
        cc[cfg] = (int)corrT[cfg * C_OUT + o];

#pragma unroll
    for (int g = 0; g < 2; ++g) {                    // two 16-pixel groups
#pragma unroll 4
        for (int pi = 0; pi < 16; ++pi) {
            int s = s0 + g * 16 + pi;                // wave-uniform pixel
            int h = s / WW_;
            int w = s - h * WW_;

            int acc = 0;
#pragma unroll
            for (int r = 0; r < 3; ++r) {
                // uniform address -> scalar loads (s_load_dwordx8), xor reads SGPR
                const uint32_t* pr = xp + (((size_t)n * PH + h + r) * PW + w) * WORDS;
#pragma unroll
                for (int t = 0; t < 3; ++t) {
#pragma unroll
                    for (int j = 0; j < WORDS; ++j)
                        acc += __popc(pr[t * WORDS + j] ^ wreg[(r * 3 + t) * WORDS + j]);
                }
            }

            int hp = (h == 0) ? 0 : ((h == HH - 1) ? 2 : 1);
            int wq = (w == 0) ? 0 : ((w == WW_ - 1) ? 2 : 1);
            int cfg = hp * 3 + wq;                   // wave-uniform
            int corrV;
            switch (cfg) {                            // uniform branch tree, static idx
                case 0: corrV = cc[0]; break;
                case 1: corrV = cc[1]; break;
                case 2: corrV = cc[2]; break;
                case 3: corrV = cc[3]; break;
                case 4: corrV = cc[4]; break;
                case 5: corrV = cc[5]; break;
                case 6: corrV = cc[6]; break;
                case 7: corrV = cc[7]; break;
                default: corrV = cc[8]; break;
            }
            lds[wv][pi][lane] = (float)(corrV - 2 * acc);
        }
        // transpose-out: 16 px x 64 o -> coalesced global stores (4 o-rows x 64B each)
#pragma unroll
        for (int k = 0; k < 16; ++k) {
            int oo = k * 4 + (lane >> 4);            // 0..63
            int ss = s0 + g * 16 + (lane & 15);
            out[((size_t)n * C_OUT + wv * 64 + oo) * HW + ss] = lds[wv][lane & 15][oo];
        }
    }
}

extern "C" void kernel_launch(void* const* d_in, const int* in_sizes, int n_in,
                              void* d_out, int out_size, void* d_ws, size_t ws_size,
                              hipStream_t stream) {
    const float* x = (const float*)d_in[0];
    const float* w = (const float*)d_in[1];
    float* out = (float*)d_out;

    uint32_t* xp    = (uint32_t*)d_ws;                        // 32*58*58*8 u32
    uint32_t* wp    = xp + (size_t)N_BATCH * PH * PW * WORDS; // 18432 u32
    uint32_t* corrT = wp + (size_t)C_OUT * TAPS * WORDS;      // 2304 u32

    hipMemsetAsync(xp, 0, (size_t)N_BATCH * PH * PW * WORDS * sizeof(uint32_t), stream);

    pack_x_kernel<<<dim3(HW * N_BATCH * WORDS / 256), 256, 0, stream>>>(x, xp);
    pack_w_kernel<<<dim3(C_OUT * TAPS * WORDS / 256), 256, 0, stream>>>(w, wp);
    corr_kernel<<<dim3(1), 256, 0, stream>>>(wp, corrT);

    bconv2_kernel<<<dim3(HW / CHUNK, N_BATCH), dim3(64, 4), 0, stream>>>(xp, wp, corrT, out);
}